// Round 12
// baseline (2151.771 us; speedup 1.0000x reference)
//
#include <hip/hip_runtime.h>

__device__ __forceinline__ float bflo(unsigned w) { return __uint_as_float(w << 16); }
__device__ __forceinline__ float bfhi(unsigned w) { return __uint_as_float(w & 0xffff0000u); }

// ws layout (float offsets):
//   Wcx  [7][2048]        @ 0       fp32 xz-feedback fold (one-time reg load)
//   WtsT [14][1024]       @ 14336   fp32 (one-time reg load)
//   bts  [14] (+pad)      @ 28672
//   WxpP [512][160] uint  @ 28688   bf16-pair packed W_xproj (per-step stream)
//   WdtP [16][1024] uint  @ 110608  bf16-pair packed W_dt    (per-step stream)
// total 126992 floats = 507968 B
#define WS_WCX  0
#define WS_WTST 14336
#define WS_BTS  28672
#define WS_WXPP 28688
#define WS_WDTP 110608

// ---------------- one-time weight folds + bf16 packs ----------------
__global__ __launch_bounds__(256) void k_fold(
    const float* __restrict__ W_feat, const float* __restrict__ W_inproj,
    const float* __restrict__ Wout, const float* __restrict__ Wtr,
    const float* __restrict__ Wse, const float* __restrict__ b_out,
    const float* __restrict__ b_tr, const float* __restrict__ b_se,
    const float* __restrict__ Wxp, const float* __restrict__ Wdt,
    float* __restrict__ ws) {
  const int b = blockIdx.x, t = threadIdx.x;
  unsigned* wsu = reinterpret_cast<unsigned*>(ws);
  if (b < 8) {                       // Wcx[i][j] = sum_k W_feat[512+i][k] W_inproj[k][j]
    int j = b * 256 + t;
    float acc[7] = {0, 0, 0, 0, 0, 0, 0};
    for (int k = 0; k < 512; ++k) {
      float wi = W_inproj[(size_t)k * 2048 + j];
#pragma unroll
      for (int i = 0; i < 7; ++i) acc[i] += W_feat[(size_t)(512 + i) * 512 + k] * wi;
    }
#pragma unroll
    for (int i = 0; i < 7; ++i) ws[WS_WCX + i * 2048 + j] = acc[i];
  } else if (b < 12) {               // WtsT[c][k] = sum_o Wout[k][o]*[Wtr|Wse][o][c]
    int k = (b - 8) * 256 + t;
    float acc[14];
#pragma unroll
    for (int c = 0; c < 14; ++c) acc[c] = 0.f;
    const float* wo = Wout + (size_t)k * 512;
    for (int o = 0; o < 512; ++o) {
      float w = wo[o];
      const float* tr = Wtr + o * 7;
      const float* se = Wse + o * 7;
#pragma unroll
      for (int c = 0; c < 7; ++c) { acc[c] += w * tr[c]; acc[7 + c] += w * se[c]; }
    }
#pragma unroll
    for (int c = 0; c < 14; ++c) ws[WS_WTST + c * 1024 + k] = acc[c];
  } else if (b == 12) {              // bts
    if (t < 14) {
      int c = (t < 7) ? t : t - 7;
      const float* W = (t < 7) ? Wtr : Wse;
      float s = (t < 7) ? b_tr[t] : b_se[t - 7];
      for (int o = 0; o < 512; ++o) s += b_out[o] * W[o * 7 + c];
      ws[WS_BTS + t] = s;
    }
  } else if (b < 333) {              // WxpP: pack k-pairs, RNE
    int idx = (b - 13) * 256 + t;    // [0, 81920)
    int k2 = idx / 160, p = idx - k2 * 160;
    unsigned ua = __float_as_uint(Wxp[(size_t)(2 * k2) * 160 + p]);
    unsigned ub = __float_as_uint(Wxp[(size_t)(2 * k2 + 1) * 160 + p]);
    ua += 0x7fffu + ((ua >> 16) & 1u);
    ub += 0x7fffu + ((ub >> 16) & 1u);
    wsu[WS_WXPP + idx] = (ua >> 16) | (ub & 0xffff0000u);
  } else {                           // WdtP: pack q-pairs, RNE
    int idx = (b - 333) * 256 + t;   // [0, 16384)
    int q2 = idx >> 10, o = idx & 1023;
    unsigned ua = __float_as_uint(Wdt[(size_t)(2 * q2) * 1024 + o]);
    unsigned ub = __float_as_uint(Wdt[(size_t)(2 * q2 + 1) * 1024 + o]);
    ua += 0x7fffu + ((ua >> 16) & 1u);
    ub += 0x7fffu + ((ub >> 16) & 1u);
    wsu[WS_WDTP + idx] = (ua >> 16) | (ub & 0xffff0000u);
  }
}

// ---------------- persistent scan: 256 blocks x 1024 thr, 4 rows/block ------
struct Pro {                        // prologue-only
  float x2[4][1024];                // 16K
  float hb[4][512];                 // 8K
  float hin[4][512];                // 8K
  float hpart[2][4][512];           // 16K
};
struct Sc {                         // scan-phase
  float xc[4][1024];                // 16K
  float part2[16][4][168];          // 43K (168-pad: row starts rotate 8 banks)
  float proj[4][32];                // 512B
  float combs[4][8];
  float bcv[4];
  float ts[4][16];
};
union SMem { Pro pro; Sc sc; };

__global__ __launch_bounds__(1024) void k_scan(
    const float* __restrict__ tc, const float* __restrict__ cc,
    const float* __restrict__ initv,
    const float* __restrict__ W_cf, const float* __restrict__ b_cf,
    const float* __restrict__ ln_g, const float* __restrict__ ln_b,
    const float* __restrict__ W_feat, const float* __restrict__ b_feat,
    const float* __restrict__ W_inproj, const float* __restrict__ b_inproj,
    const float* __restrict__ conv_w, const float* __restrict__ conv_b,
    const float* __restrict__ b_dt, const float* __restrict__ D_param,
    const float* __restrict__ W_fin, const float* __restrict__ b_fin,
    const float* __restrict__ ws, float* __restrict__ out) {
  __shared__ SMem S;
  const unsigned* wsu = reinterpret_cast<const unsigned*>(ws);
  const int t = threadIdx.x;          // 0..1023
  const int r0 = blockIdx.x * 4;
  const int o9 = t & 511;
  const int kc9 = t >> 9;

  // ================= prologue =================
  for (int idx = t; idx < 4096; idx += 1024) {
    int r = idx >> 10, k = idx & 1023;
    S.pro.x2[r][k] = (k < 512) ? tc[(size_t)(r0 + r) * 512 + k]
                               : cc[(size_t)(r0 + r) * 512 + (k - 512)];
  }
  __syncthreads();
  // h = relu([tc,cc] @ W_cf + b_cf), K split 2x512
  {
    const float* wp = W_cf + (size_t)(kc9 * 512) * 512 + o9;
    int k0 = kc9 * 512;
    float a0 = 0, a1 = 0, a2 = 0, a3 = 0;
    for (int k = k0; k < k0 + 512; ++k) {
      float w = wp[0]; wp += 512;
      a0 += S.pro.x2[0][k] * w; a1 += S.pro.x2[1][k] * w;
      a2 += S.pro.x2[2][k] * w; a3 += S.pro.x2[3][k] * w;
    }
    S.pro.hpart[kc9][0][o9] = a0; S.pro.hpart[kc9][1][o9] = a1;
    S.pro.hpart[kc9][2][o9] = a2; S.pro.hpart[kc9][3][o9] = a3;
  }
  __syncthreads();
  {
    float b = b_cf[o9];
#pragma unroll
    for (int rr = 0; rr < 2; ++rr) {
      int r = kc9 * 2 + rr;
      S.pro.hb[r][o9] = fmaxf(S.pro.hpart[0][r][o9] + S.pro.hpart[1][r][o9] + b, 0.f);
    }
  }
  __syncthreads();
  // LayerNorm
  if (t < 256) {
    int w = t >> 6, lane = t & 63;
    float s = 0.f, s2 = 0.f;
    for (int j = lane; j < 512; j += 64) { float v = S.pro.hb[w][j]; s += v; s2 += v * v; }
#pragma unroll
    for (int off = 32; off; off >>= 1) { s += __shfl_xor(s, off); s2 += __shfl_xor(s2, off); }
    float mu = s * (1.f / 512.f);
    float var = s2 * (1.f / 512.f) - mu * mu;
    float inv = rsqrtf(var + 1e-5f);
    for (int j = lane; j < 512; j += 64)
      S.pro.hb[w][j] = (S.pro.hb[w][j] - mu) * inv * ln_g[j] + ln_b[j];
  }
  __syncthreads();
  // hin = fused @ W_feat[:512] + b_feat, K split 2x256
  {
    int k0 = kc9 * 256;
    const float* wp = W_feat + (size_t)k0 * 512 + o9;
    float a0 = 0, a1 = 0, a2 = 0, a3 = 0;
    for (int k = k0; k < k0 + 256; ++k) {
      float w = wp[0]; wp += 512;
      a0 += S.pro.hb[0][k] * w; a1 += S.pro.hb[1][k] * w;
      a2 += S.pro.hb[2][k] * w; a3 += S.pro.hb[3][k] * w;
    }
    S.pro.hpart[kc9][0][o9] = a0; S.pro.hpart[kc9][1][o9] = a1;
    S.pro.hpart[kc9][2][o9] = a2; S.pro.hpart[kc9][3][o9] = a3;
  }
  __syncthreads();
  {
    float b = b_feat[o9];
#pragma unroll
    for (int rr = 0; rr < 2; ++rr) {
      int r = kc9 * 2 + rr;
      S.pro.hin[r][o9] = S.pro.hpart[0][r][o9] + S.pro.hpart[1][r][o9] + b;
    }
  }
  __syncthreads();

  // xz_base: thread t owns cols t (x half) and 1024+t (z half), 4 rows
  float xzbx[4], xzbz[4];
#pragma unroll
  for (int half = 0; half < 2; ++half) {
    int col = t + half * 1024;
    const float* wp = W_inproj + col;
    float a0 = 0, a1 = 0, a2 = 0, a3 = 0;
    for (int k = 0; k < 512; ++k) {
      float wi = wp[0]; wp += 2048;
      a0 += S.pro.hin[0][k] * wi; a1 += S.pro.hin[1][k] * wi;
      a2 += S.pro.hin[2][k] * wi; a3 += S.pro.hin[3][k] * wi;
    }
    float bi = b_inproj[col];
    if (half == 0) { xzbx[0] = a0 + bi; xzbx[1] = a1 + bi; xzbx[2] = a2 + bi; xzbx[3] = a3 + bi; }
    else           { xzbz[0] = a0 + bi; xzbz[1] = a1 + bi; xzbz[2] = a2 + bi; xzbz[3] = a3 + bi; }
  }

  // ---- step-invariant per-thread constants (one-time reads) ----
  float wcxx[7], wcxz[7];
#pragma unroll
  for (int i = 0; i < 7; ++i) {
    wcxx[i] = ws[WS_WCX + i * 2048 + t];
    wcxz[i] = ws[WS_WCX + i * 2048 + 1024 + t];
  }
  const float cw3  = conv_w[t * 4 + 3];
  const float cbv  = conv_b[t];
  const float dpar = D_param[t];
  const float bdtv = b_dt[t];
  const int wv = t >> 6, ln = t & 63;
  float wts[16], btsw = 0.f;
  if (wv < 14) {
#pragma unroll
    for (int i = 0; i < 16; ++i) wts[i] = ws[WS_WTST + wv * 1024 + ln + i * 64];
    btsw = ws[WS_BTS + wv];
  } else {
#pragma unroll
    for (int i = 0; i < 16; ++i) wts[i] = 0.f;
  }

  if (t < 28) S.sc.combs[t / 7][t % 7] = initv[(r0 + t / 7) * 7 + (t % 7)];
  __syncthreads();

  // ================= 64 sequential decode steps =================
  float zsr[4], xcr[4];
  for (int step = 0; step < 64; ++step) {
    // P1: xz = xz_base + comb @ Wcx; x_c = silu(conv) -> LDS+reg; silu(z) -> reg
#pragma unroll
    for (int r = 0; r < 4; ++r) {
      float v = xzbx[r], u = xzbz[r];
#pragma unroll
      for (int i = 0; i < 7; ++i) {
        float cb_ = S.sc.combs[r][i];
        v += cb_ * wcxx[i];
        u += cb_ * wcxz[i];
      }
      v = v * cw3 + cbv;
      float sv = v / (1.f + __expf(-v));
      xcr[r] = sv;
      S.sc.xc[r][t] = sv;
      zsr[r] = u / (1.f + __expf(-u));
    }
    __syncthreads();

    // P2: x_c @ Wxp (bf16 pairs). 640 thr = 16 k2-chunks(32) x 40 col-quads.
    // One uint4 load = 8 weights = 32 FMAs (4 cols x 2 k x 4 rows).
    if (t < 640) {
      int kc = t / 40, g = t - kc * 40;     // kc 0..15, g 0..39
      int k2base = kc * 32, kbase = kc * 64;
      const uint4* wp = reinterpret_cast<const uint4*>(wsu + WS_WXPP + (size_t)k2base * 160 + 4 * g);
      const float2* x0 = reinterpret_cast<const float2*>(&S.sc.xc[0][kbase]);
      const float2* x1 = reinterpret_cast<const float2*>(&S.sc.xc[1][kbase]);
      const float2* x2 = reinterpret_cast<const float2*>(&S.sc.xc[2][kbase]);
      const float2* x3 = reinterpret_cast<const float2*>(&S.sc.xc[3][kbase]);
      float a00 = 0, a01 = 0, a02 = 0, a03 = 0;   // a<col><row>
      float a10 = 0, a11 = 0, a12 = 0, a13 = 0;
      float a20 = 0, a21 = 0, a22 = 0, a23 = 0;
      float a30 = 0, a31 = 0, a32 = 0, a33 = 0;
#pragma unroll 8
      for (int i = 0; i < 32; ++i) {
        uint4 w = wp[(size_t)i * 40];
        float2 v0 = x0[i], v1 = x1[i], v2 = x2[i], v3 = x3[i];
        float wl, wh;
        wl = bflo(w.x); wh = bfhi(w.x);
        a00 += wl * v0.x + wh * v0.y; a01 += wl * v1.x + wh * v1.y;
        a02 += wl * v2.x + wh * v2.y; a03 += wl * v3.x + wh * v3.y;
        wl = bflo(w.y); wh = bfhi(w.y);
        a10 += wl * v0.x + wh * v0.y; a11 += wl * v1.x + wh * v1.y;
        a12 += wl * v2.x + wh * v2.y; a13 += wl * v3.x + wh * v3.y;
        wl = bflo(w.z); wh = bfhi(w.z);
        a20 += wl * v0.x + wh * v0.y; a21 += wl * v1.x + wh * v1.y;
        a22 += wl * v2.x + wh * v2.y; a23 += wl * v3.x + wh * v3.y;
        wl = bflo(w.w); wh = bfhi(w.w);
        a30 += wl * v0.x + wh * v0.y; a31 += wl * v1.x + wh * v1.y;
        a32 += wl * v2.x + wh * v2.y; a33 += wl * v3.x + wh * v3.y;
      }
      float4* pr0 = reinterpret_cast<float4*>(&S.sc.part2[kc][0][4 * g]);
      float4* pr1 = reinterpret_cast<float4*>(&S.sc.part2[kc][1][4 * g]);
      float4* pr2 = reinterpret_cast<float4*>(&S.sc.part2[kc][2][4 * g]);
      float4* pr3 = reinterpret_cast<float4*>(&S.sc.part2[kc][3][4 * g]);
      *pr0 = make_float4(a00, a10, a20, a30);
      *pr1 = make_float4(a01, a11, a21, a31);
      *pr2 = make_float4(a02, a12, a22, a32);
      *pr3 = make_float4(a03, a13, a23, a33);
    }
    __syncthreads();

    // reduce dt_r (cols 0..31) + bc = <Bm,Cm> (cols 32..159)
    if (t < 128) {
      int r = t >> 5, p = t & 31;
      float s = 0.f;
#pragma unroll
      for (int c = 0; c < 16; ++c) s += S.sc.part2[c][r][p];
      S.sc.proj[r][p] = s;
    } else if (t >= 256 && t < 512) {
      int r = (t - 256) >> 6, n = t & 63;
      float bm = 0.f, cm = 0.f;
#pragma unroll
      for (int c = 0; c < 16; ++c) {
        bm += S.sc.part2[c][r][32 + n];
        cm += S.sc.part2[c][r][96 + n];
      }
      float pr = bm * cm;
#pragma unroll
      for (int off = 32; off; off >>= 1) pr += __shfl_xor(pr, off);
      if (n == 0) S.sc.bcv[r] = pr;
    }
    __syncthreads();

    // P3: dt = softplus(dt_r @ W_dt + b_dt) with bf16-pair Wdt; y -> xc
    {
      const unsigned* wp = wsu + WS_WDTP + t;
      const float2* p0 = reinterpret_cast<const float2*>(&S.sc.proj[0][0]);
      const float2* p1 = reinterpret_cast<const float2*>(&S.sc.proj[1][0]);
      const float2* p2 = reinterpret_cast<const float2*>(&S.sc.proj[2][0]);
      const float2* p3 = reinterpret_cast<const float2*>(&S.sc.proj[3][0]);
      float a0 = bdtv, a1 = bdtv, a2 = bdtv, a3 = bdtv;
#pragma unroll
      for (int q2 = 0; q2 < 16; ++q2) {
        unsigned w = wp[q2 * 1024];
        float w0 = bflo(w), w1 = bfhi(w);
        float2 q0 = p0[q2], q1 = p1[q2], q2v = p2[q2], q3 = p3[q2];
        a0 += q0.x * w0 + q0.y * w1;
        a1 += q1.x * w0 + q1.y * w1;
        a2 += q2v.x * w0 + q2v.y * w1;
        a3 += q3.x * w0 + q3.y * w1;
      }
      float accs[4] = {a0, a1, a2, a3};
#pragma unroll
      for (int r = 0; r < 4; ++r) {
        float v = accs[r];
        float sp = fmaxf(v, 0.f) + log1pf(__expf(-fabsf(v)));
        S.sc.xc[r][t] = (sp * S.sc.bcv[r] + dpar) * xcr[r] * zsr[r];
      }
    }
    __syncthreads();

    // Pts: ts = y @ Wts + bts (weights in registers)
    if (wv < 14) {
      float a0 = 0, a1 = 0, a2 = 0, a3 = 0;
#pragma unroll
      for (int i = 0; i < 16; ++i) {
        int k = ln + i * 64;
        float wt = wts[i];
        a0 += S.sc.xc[0][k] * wt; a1 += S.sc.xc[1][k] * wt;
        a2 += S.sc.xc[2][k] * wt; a3 += S.sc.xc[3][k] * wt;
      }
#pragma unroll
      for (int off = 32; off; off >>= 1) {
        a0 += __shfl_xor(a0, off); a1 += __shfl_xor(a1, off);
        a2 += __shfl_xor(a2, off); a3 += __shfl_xor(a3, off);
      }
      if (ln == 0) {
        float v0 = a0 + btsw, v1 = a1 + btsw, v2 = a2 + btsw, v3 = a3 + btsw;
        S.sc.ts[0][wv] = v0; S.sc.ts[1][wv] = v1;
        S.sc.ts[2][wv] = v2; S.sc.ts[3][wv] = v3;
        float vals[4] = {v0, v1, v2, v3};
#pragma unroll
        for (int r = 0; r < 4; ++r) {
          size_t idx = ((size_t)(r0 + r) * 64 + step) * 7;
          if (wv < 7) out[idx + wv] = vals[r];
          else out[458752 + idx + (wv - 7)] = vals[r];
        }
      }
    }
    __syncthreads();

    // P7: comb = [trend,seas] @ W_fin + b_fin, write out + feedback
    if (t < 28) {
      int r = t / 7, c = t - (t / 7) * 7;
      float s = b_fin[c];
#pragma unroll
      for (int i = 0; i < 14; ++i) s += S.sc.ts[r][i] * W_fin[i * 7 + c];
      S.sc.combs[r][c] = s;
      out[917504 + ((size_t)(r0 + r) * 64 + step) * 7 + c] = s;
    }
    __syncthreads();
  }
}

extern "C" void kernel_launch(void* const* d_in, const int* in_sizes, int n_in,
                              void* d_out, int out_size, void* d_ws, size_t ws_size,
                              hipStream_t stream) {
  const float* tc       = (const float*)d_in[0];
  const float* cc       = (const float*)d_in[1];
  const float* initv    = (const float*)d_in[2];
  const float* W_cf     = (const float*)d_in[3];
  const float* b_cf     = (const float*)d_in[4];
  const float* ln_g     = (const float*)d_in[5];
  const float* ln_b     = (const float*)d_in[6];
  const float* W_feat   = (const float*)d_in[7];
  const float* b_feat   = (const float*)d_in[8];
  const float* W_inproj = (const float*)d_in[9];
  const float* b_inproj = (const float*)d_in[10];
  const float* conv_w   = (const float*)d_in[11];
  const float* conv_b   = (const float*)d_in[12];
  const float* W_xproj  = (const float*)d_in[13];
  const float* W_dt     = (const float*)d_in[14];
  const float* b_dt     = (const float*)d_in[15];
  const float* D_param  = (const float*)d_in[16];
  const float* W_out    = (const float*)d_in[17];
  const float* b_out    = (const float*)d_in[18];
  const float* W_tr     = (const float*)d_in[19];
  const float* b_tr     = (const float*)d_in[20];
  const float* W_se     = (const float*)d_in[21];
  const float* b_se     = (const float*)d_in[22];
  const float* W_fin    = (const float*)d_in[23];
  const float* b_fin    = (const float*)d_in[24];

  float* ws = (float*)d_ws;   // needs 507968 B

  hipLaunchKernelGGL(k_fold, dim3(397), dim3(256), 0, stream,
                     W_feat, W_inproj, W_out, W_tr, W_se, b_out, b_tr, b_se,
                     W_xproj, W_dt, ws);
  hipLaunchKernelGGL(k_scan, dim3(256), dim3(1024), 0, stream,
                     tc, cc, initv, W_cf, b_cf, ln_g, ln_b, W_feat, b_feat,
                     W_inproj, b_inproj, conv_w, conv_b, b_dt, D_param,
                     W_fin, b_fin, ws, (float*)d_out);
}

// Round 13
// 1390.538 us; speedup vs baseline: 1.5474x; 1.5474x over previous
//
#include <hip/hip_runtime.h>

typedef _Float16 h2 __attribute__((ext_vector_type(2)));
union U32H2 { unsigned u; h2 h; };
__device__ __forceinline__ h2 u2h(unsigned u) { U32H2 x; x.u = u; return x.h; }

#if __has_builtin(__builtin_amdgcn_fdot2)
__device__ __forceinline__ float fdot2(h2 a, h2 b, float c) {
  return __builtin_amdgcn_fdot2(a, b, c, false);
}
#else
__device__ __forceinline__ float fdot2(h2 a, h2 b, float c) {
  return c + (float)a[0] * (float)b[0] + (float)a[1] * (float)b[1];
}
#endif

__device__ __forceinline__ unsigned packf16(float a, float b) {
  unsigned short pa = __builtin_bit_cast(unsigned short, (_Float16)a);
  unsigned short pb = __builtin_bit_cast(unsigned short, (_Float16)b);
  return (unsigned)pa | ((unsigned)pb << 16);
}

// ws layout (float offsets):
//   Wcx   [7][2048]       @ 0       fp32 xz-feedback fold
//   WtsT  [21][1024]      @ 14336   fp32: cols 0..13 = (W_out@[W_tr|W_se])^T,
//                                        cols 14..20 = (W_out@[W_tr|W_se]@W_fin)^T
//   bts   [21]+pad        @ 35840   matching biases
//   WxpP  [512][160] uint @ 35872   f16-pair packed W_xproj (per-step stream)
//   WdtP  [16][1024] uint @ 117792  f16-pair packed W_dt    (per-step stream)
#define WS_WCX  0
#define WS_WTST 14336
#define WS_BTS  35840
#define WS_WXPP 35872
#define WS_WDTP 117792
// total 134176 floats = 536704 B

// ---------------- one-time weight folds + f16 packs ----------------
__global__ __launch_bounds__(256) void k_fold(
    const float* __restrict__ W_feat, const float* __restrict__ W_inproj,
    const float* __restrict__ Wout, const float* __restrict__ Wtr,
    const float* __restrict__ Wse, const float* __restrict__ b_out,
    const float* __restrict__ b_tr, const float* __restrict__ b_se,
    const float* __restrict__ W_fin, const float* __restrict__ b_fin,
    const float* __restrict__ Wxp, const float* __restrict__ Wdt,
    float* __restrict__ ws) {
  const int b = blockIdx.x, t = threadIdx.x;
  unsigned* wsu = reinterpret_cast<unsigned*>(ws);
  if (b < 8) {                       // Wcx[i][j] = sum_k W_feat[512+i][k] W_inproj[k][j]
    int j = b * 256 + t;
    float acc[7] = {0, 0, 0, 0, 0, 0, 0};
    for (int k = 0; k < 512; ++k) {
      float wi = W_inproj[(size_t)k * 2048 + j];
#pragma unroll
      for (int i = 0; i < 7; ++i) acc[i] += W_feat[(size_t)(512 + i) * 512 + k] * wi;
    }
#pragma unroll
    for (int i = 0; i < 7; ++i) ws[WS_WCX + i * 2048 + j] = acc[i];
  } else if (b < 12) {               // WtsT 21 cols
    __shared__ float Ush[512][7];    // U[o][c] = sum_j [Wtr|Wse][o][j] * W_fin[j][c]
    for (int o = t; o < 512; o += 256) {
      float u[7] = {0, 0, 0, 0, 0, 0, 0};
#pragma unroll
      for (int j = 0; j < 7; ++j) {
        float a = Wtr[o * 7 + j], bb = Wse[o * 7 + j];
#pragma unroll
        for (int c = 0; c < 7; ++c)
          u[c] += a * W_fin[j * 7 + c] + bb * W_fin[(7 + j) * 7 + c];
      }
#pragma unroll
      for (int c = 0; c < 7; ++c) Ush[o][c] = u[c];
    }
    __syncthreads();
    int k = (b - 8) * 256 + t;
    float acc[21];
#pragma unroll
    for (int c = 0; c < 21; ++c) acc[c] = 0.f;
    const float* wo = Wout + (size_t)k * 512;
    for (int o = 0; o < 512; ++o) {
      float w = wo[o];
      const float* tr = Wtr + o * 7;
      const float* se = Wse + o * 7;
#pragma unroll
      for (int c = 0; c < 7; ++c) {
        acc[c] += w * tr[c]; acc[7 + c] += w * se[c]; acc[14 + c] += w * Ush[o][c];
      }
    }
#pragma unroll
    for (int c = 0; c < 21; ++c) ws[WS_WTST + c * 1024 + k] = acc[c];
  } else if (b == 12) {              // bts[0..13], btsc[14..20]
    __shared__ float btss[14];
    if (t < 14) {
      int c = (t < 7) ? t : t - 7;
      const float* W = (t < 7) ? Wtr : Wse;
      float s = (t < 7) ? b_tr[t] : b_se[t - 7];
      for (int o = 0; o < 512; ++o) s += b_out[o] * W[o * 7 + c];
      btss[t] = s;
      ws[WS_BTS + t] = s;
    }
    __syncthreads();
    if (t < 7) {
      float s = b_fin[t];
#pragma unroll
      for (int j = 0; j < 14; ++j) s += btss[j] * W_fin[j * 7 + t];
      ws[WS_BTS + 14 + t] = s;
    }
  } else if (b < 333) {              // WxpP: f16 k-pairs
    int idx = (b - 13) * 256 + t;    // [0, 81920)
    int k2 = idx / 160, p = idx - k2 * 160;
    wsu[WS_WXPP + idx] = packf16(Wxp[(size_t)(2 * k2) * 160 + p],
                                 Wxp[(size_t)(2 * k2 + 1) * 160 + p]);
  } else {                           // WdtP: f16 q-pairs
    int idx = (b - 333) * 256 + t;   // [0, 16384)
    int q2 = idx >> 10, o = idx & 1023;
    wsu[WS_WDTP + idx] = packf16(Wdt[(size_t)(2 * q2) * 1024 + o],
                                 Wdt[(size_t)(2 * q2 + 1) * 1024 + o]);
  }
}

// ---------------- persistent scan: 256 blocks x 1024 thr, 4 rows/block ------
struct Pro {                        // prologue-only
  float x2[4][1024];                // 16K
  float hb[4][512];                 // 8K
  float hin[4][512];                // 8K
  float hpart[2][4][512];           // 16K
};
struct Sc {                         // scan-phase
  float xc[4][1024];                // 16K  y (f32, Pts input)
  _Float16 xch[4][1024];            // 8K   x_c (f16, P2 input)
  float part2[16][4][168];          // 43K
  _Float16 projh[4][32];            // 256B dt_r (f16, P3 input)
  float combs[4][8];
  float bcv[4];
};
union SMem { Pro pro; Sc sc; };

__global__ __launch_bounds__(1024) void k_scan(
    const float* __restrict__ tc, const float* __restrict__ cc,
    const float* __restrict__ initv,
    const float* __restrict__ W_cf, const float* __restrict__ b_cf,
    const float* __restrict__ ln_g, const float* __restrict__ ln_b,
    const float* __restrict__ W_feat, const float* __restrict__ b_feat,
    const float* __restrict__ W_inproj, const float* __restrict__ b_inproj,
    const float* __restrict__ conv_w, const float* __restrict__ conv_b,
    const float* __restrict__ b_dt, const float* __restrict__ D_param,
    const float* __restrict__ ws, float* __restrict__ out) {
  __shared__ SMem S;
  const unsigned* wsu = reinterpret_cast<const unsigned*>(ws);
  const int t = threadIdx.x;          // 0..1023
  const int r0 = blockIdx.x * 4;
  const int o9 = t & 511;
  const int kc9 = t >> 9;

  // ================= prologue =================
  for (int idx = t; idx < 4096; idx += 1024) {
    int r = idx >> 10, k = idx & 1023;
    S.pro.x2[r][k] = (k < 512) ? tc[(size_t)(r0 + r) * 512 + k]
                               : cc[(size_t)(r0 + r) * 512 + (k - 512)];
  }
  __syncthreads();
  // h = relu([tc,cc] @ W_cf + b_cf), K split 2x512
  {
    const float* wp = W_cf + (size_t)(kc9 * 512) * 512 + o9;
    int k0 = kc9 * 512;
    float a0 = 0, a1 = 0, a2 = 0, a3 = 0;
    for (int k = k0; k < k0 + 512; ++k) {
      float w = wp[0]; wp += 512;
      a0 += S.pro.x2[0][k] * w; a1 += S.pro.x2[1][k] * w;
      a2 += S.pro.x2[2][k] * w; a3 += S.pro.x2[3][k] * w;
    }
    S.pro.hpart[kc9][0][o9] = a0; S.pro.hpart[kc9][1][o9] = a1;
    S.pro.hpart[kc9][2][o9] = a2; S.pro.hpart[kc9][3][o9] = a3;
  }
  __syncthreads();
  {
    float b = b_cf[o9];
#pragma unroll
    for (int rr = 0; rr < 2; ++rr) {
      int r = kc9 * 2 + rr;
      S.pro.hb[r][o9] = fmaxf(S.pro.hpart[0][r][o9] + S.pro.hpart[1][r][o9] + b, 0.f);
    }
  }
  __syncthreads();
  // LayerNorm
  if (t < 256) {
    int w = t >> 6, lane = t & 63;
    float s = 0.f, s2 = 0.f;
    for (int j = lane; j < 512; j += 64) { float v = S.pro.hb[w][j]; s += v; s2 += v * v; }
#pragma unroll
    for (int off = 32; off; off >>= 1) { s += __shfl_xor(s, off); s2 += __shfl_xor(s2, off); }
    float mu = s * (1.f / 512.f);
    float var = s2 * (1.f / 512.f) - mu * mu;
    float inv = rsqrtf(var + 1e-5f);
    for (int j = lane; j < 512; j += 64)
      S.pro.hb[w][j] = (S.pro.hb[w][j] - mu) * inv * ln_g[j] + ln_b[j];
  }
  __syncthreads();
  // hin = fused @ W_feat[:512] + b_feat, K split 2x256
  {
    int k0 = kc9 * 256;
    const float* wp = W_feat + (size_t)k0 * 512 + o9;
    float a0 = 0, a1 = 0, a2 = 0, a3 = 0;
    for (int k = k0; k < k0 + 256; ++k) {
      float w = wp[0]; wp += 512;
      a0 += S.pro.hb[0][k] * w; a1 += S.pro.hb[1][k] * w;
      a2 += S.pro.hb[2][k] * w; a3 += S.pro.hb[3][k] * w;
    }
    S.pro.hpart[kc9][0][o9] = a0; S.pro.hpart[kc9][1][o9] = a1;
    S.pro.hpart[kc9][2][o9] = a2; S.pro.hpart[kc9][3][o9] = a3;
  }
  __syncthreads();
  {
    float b = b_feat[o9];
#pragma unroll
    for (int rr = 0; rr < 2; ++rr) {
      int r = kc9 * 2 + rr;
      S.pro.hin[r][o9] = S.pro.hpart[0][r][o9] + S.pro.hpart[1][r][o9] + b;
    }
  }
  __syncthreads();

  // xz_base: thread t owns cols t (x half) and 1024+t (z half), 4 rows
  float xzbx[4], xzbz[4];
#pragma unroll
  for (int half = 0; half < 2; ++half) {
    int col = t + half * 1024;
    const float* wp = W_inproj + col;
    float a0 = 0, a1 = 0, a2 = 0, a3 = 0;
    for (int k = 0; k < 512; ++k) {
      float wi = wp[0]; wp += 2048;
      a0 += S.pro.hin[0][k] * wi; a1 += S.pro.hin[1][k] * wi;
      a2 += S.pro.hin[2][k] * wi; a3 += S.pro.hin[3][k] * wi;
    }
    float bi = b_inproj[col];
    if (half == 0) { xzbx[0] = a0 + bi; xzbx[1] = a1 + bi; xzbx[2] = a2 + bi; xzbx[3] = a3 + bi; }
    else           { xzbz[0] = a0 + bi; xzbz[1] = a1 + bi; xzbz[2] = a2 + bi; xzbz[3] = a3 + bi; }
  }

  // ---- step-invariant per-thread constants (one-time reads) ----
  float wcxx[7], wcxz[7];
#pragma unroll
  for (int i = 0; i < 7; ++i) {
    wcxx[i] = ws[WS_WCX + i * 2048 + t];
    wcxz[i] = ws[WS_WCX + i * 2048 + 1024 + t];
  }
  const float cw3  = conv_w[t * 4 + 3];
  const float cbv  = conv_b[t];
  const float dpar = D_param[t];
  const float bdtv = b_dt[t];
  // Pts weights in registers. Wave wv: colA = wv (ts, wv<14); colB = wv+5 (comb, wv>=9)
  const int wv = t >> 6, ln = t & 63;
  float wtsA[16], btsA = 0.f, wtsB[16], btsB = 0.f;
  if (wv < 14) {
#pragma unroll
    for (int i = 0; i < 16; ++i) wtsA[i] = ws[WS_WTST + wv * 1024 + ln + i * 64];
    btsA = ws[WS_BTS + wv];
  } else {
#pragma unroll
    for (int i = 0; i < 16; ++i) wtsA[i] = 0.f;
  }
  if (wv >= 9) {
#pragma unroll
    for (int i = 0; i < 16; ++i) wtsB[i] = ws[WS_WTST + (wv + 5) * 1024 + ln + i * 64];
    btsB = ws[WS_BTS + wv + 5];
  } else {
#pragma unroll
    for (int i = 0; i < 16; ++i) wtsB[i] = 0.f;
  }

  if (t < 28) S.sc.combs[t / 7][t % 7] = initv[(r0 + t / 7) * 7 + (t % 7)];
  __syncthreads();

  // ================= 64 sequential decode steps =================
  float zsr[4], xcr[4];
  for (int step = 0; step < 64; ++step) {
    // P1: xz = xz_base + comb @ Wcx; x_c = silu(conv) -> f16 LDS + reg; silu(z) -> reg
#pragma unroll
    for (int r = 0; r < 4; ++r) {
      float v = xzbx[r], u = xzbz[r];
#pragma unroll
      for (int i = 0; i < 7; ++i) {
        float cb_ = S.sc.combs[r][i];
        v += cb_ * wcxx[i];
        u += cb_ * wcxz[i];
      }
      v = v * cw3 + cbv;
      float sv = v / (1.f + __expf(-v));
      xcr[r] = sv;
      S.sc.xch[r][t] = (_Float16)sv;
      zsr[r] = u / (1.f + __expf(-u));
    }
    __syncthreads();

    // P2: x_c @ Wxp via f16 dot2. 640 thr = 16 k2-chunks(32) x 40 col-quads.
    if (t < 640) {
      int kc = t / 40, g = t - kc * 40;     // kc 0..15, g 0..39
      int k2base = kc * 32, kbase = kc * 64;
      const uint4* wp = reinterpret_cast<const uint4*>(wsu + WS_WXPP + (size_t)k2base * 160 + 4 * g);
      const h2* x0 = reinterpret_cast<const h2*>(&S.sc.xch[0][kbase]);
      const h2* x1 = reinterpret_cast<const h2*>(&S.sc.xch[1][kbase]);
      const h2* x2 = reinterpret_cast<const h2*>(&S.sc.xch[2][kbase]);
      const h2* x3 = reinterpret_cast<const h2*>(&S.sc.xch[3][kbase]);
      float a00 = 0, a01 = 0, a02 = 0, a03 = 0;   // a<col><row>
      float a10 = 0, a11 = 0, a12 = 0, a13 = 0;
      float a20 = 0, a21 = 0, a22 = 0, a23 = 0;
      float a30 = 0, a31 = 0, a32 = 0, a33 = 0;
#pragma unroll 8
      for (int i = 0; i < 32; ++i) {
        uint4 w = wp[(size_t)i * 40];
        h2 w0 = u2h(w.x), w1 = u2h(w.y), w2 = u2h(w.z), w3 = u2h(w.w);
        h2 v0 = x0[i], v1 = x1[i], v2 = x2[i], v3 = x3[i];
        a00 = fdot2(w0, v0, a00); a01 = fdot2(w0, v1, a01);
        a02 = fdot2(w0, v2, a02); a03 = fdot2(w0, v3, a03);
        a10 = fdot2(w1, v0, a10); a11 = fdot2(w1, v1, a11);
        a12 = fdot2(w1, v2, a12); a13 = fdot2(w1, v3, a13);
        a20 = fdot2(w2, v0, a20); a21 = fdot2(w2, v1, a21);
        a22 = fdot2(w2, v2, a22); a23 = fdot2(w2, v3, a23);
        a30 = fdot2(w3, v0, a30); a31 = fdot2(w3, v1, a31);
        a32 = fdot2(w3, v2, a32); a33 = fdot2(w3, v3, a33);
      }
      float4* pr0 = reinterpret_cast<float4*>(&S.sc.part2[kc][0][4 * g]);
      float4* pr1 = reinterpret_cast<float4*>(&S.sc.part2[kc][1][4 * g]);
      float4* pr2 = reinterpret_cast<float4*>(&S.sc.part2[kc][2][4 * g]);
      float4* pr3 = reinterpret_cast<float4*>(&S.sc.part2[kc][3][4 * g]);
      *pr0 = make_float4(a00, a10, a20, a30);
      *pr1 = make_float4(a01, a11, a21, a31);
      *pr2 = make_float4(a02, a12, a22, a32);
      *pr3 = make_float4(a03, a13, a23, a33);
    }
    __syncthreads();

    // reduce dt_r (cols 0..31) -> f16 projh; bc = <Bm,Cm> (cols 32..159)
    if (t < 128) {
      int r = t >> 5, p = t & 31;
      float s = 0.f;
#pragma unroll
      for (int c = 0; c < 16; ++c) s += S.sc.part2[c][r][p];
      S.sc.projh[r][p] = (_Float16)s;
    } else if (t >= 256 && t < 512) {
      int r = (t - 256) >> 6, n = t & 63;
      float bm = 0.f, cm = 0.f;
#pragma unroll
      for (int c = 0; c < 16; ++c) {
        bm += S.sc.part2[c][r][32 + n];
        cm += S.sc.part2[c][r][96 + n];
      }
      float pr = bm * cm;
#pragma unroll
      for (int off = 32; off; off >>= 1) pr += __shfl_xor(pr, off);
      if (n == 0) S.sc.bcv[r] = pr;
    }
    __syncthreads();

    // P3: dt = softplus(dt_r @ W_dt + b_dt) via f16 dot2; y = (dt*bc + D)*x_c*silu(z) -> xc
    {
      const unsigned* wp = wsu + WS_WDTP + t;
      const h2* p0 = reinterpret_cast<const h2*>(&S.sc.projh[0][0]);
      const h2* p1 = reinterpret_cast<const h2*>(&S.sc.projh[1][0]);
      const h2* p2 = reinterpret_cast<const h2*>(&S.sc.projh[2][0]);
      const h2* p3 = reinterpret_cast<const h2*>(&S.sc.projh[3][0]);
      float a0 = bdtv, a1 = bdtv, a2 = bdtv, a3 = bdtv;
#pragma unroll
      for (int q2 = 0; q2 < 16; ++q2) {
        h2 wh = u2h(wp[q2 * 1024]);
        a0 = fdot2(wh, p0[q2], a0);
        a1 = fdot2(wh, p1[q2], a1);
        a2 = fdot2(wh, p2[q2], a2);
        a3 = fdot2(wh, p3[q2], a3);
      }
      float accs[4] = {a0, a1, a2, a3};
#pragma unroll
      for (int r = 0; r < 4; ++r) {
        float v = accs[r];
        float sp = fmaxf(v, 0.f) + log1pf(__expf(-fabsf(v)));
        S.sc.xc[r][t] = (sp * S.sc.bcv[r] + dpar) * xcr[r] * zsr[r];
      }
    }
    __syncthreads();

    // Pts: ts/comb = y @ WtsT(21 cols) + bts. colA = wv (ts), colB = wv+5 (comb).
    {
      float a0 = 0, a1 = 0, a2 = 0, a3 = 0;
      float b0 = 0, b1 = 0, b2 = 0, b3 = 0;
#pragma unroll
      for (int i = 0; i < 16; ++i) {
        int k = ln + i * 64;
        float y0 = S.sc.xc[0][k], y1 = S.sc.xc[1][k];
        float y2 = S.sc.xc[2][k], y3 = S.sc.xc[3][k];
        float wa = wtsA[i], wb = wtsB[i];
        a0 += y0 * wa; a1 += y1 * wa; a2 += y2 * wa; a3 += y3 * wa;
        b0 += y0 * wb; b1 += y1 * wb; b2 += y2 * wb; b3 += y3 * wb;
      }
#pragma unroll
      for (int off = 32; off; off >>= 1) {
        a0 += __shfl_xor(a0, off); a1 += __shfl_xor(a1, off);
        a2 += __shfl_xor(a2, off); a3 += __shfl_xor(a3, off);
        b0 += __shfl_xor(b0, off); b1 += __shfl_xor(b1, off);
        b2 += __shfl_xor(b2, off); b3 += __shfl_xor(b3, off);
      }
      if (ln == 0) {
        if (wv < 14) {
          float v0 = a0 + btsA, v1 = a1 + btsA, v2 = a2 + btsA, v3 = a3 + btsA;
          float vals[4] = {v0, v1, v2, v3};
#pragma unroll
          for (int r = 0; r < 4; ++r) {
            size_t idx = ((size_t)(r0 + r) * 64 + step) * 7;
            if (wv < 7) out[idx + wv] = vals[r];
            else out[458752 + idx + (wv - 7)] = vals[r];
          }
        }
        if (wv >= 9) {
          int cc_ = wv - 9;   // comb col 0..6
          float v0 = b0 + btsB, v1 = b1 + btsB, v2 = b2 + btsB, v3 = b3 + btsB;
          float vals[4] = {v0, v1, v2, v3};
#pragma unroll
          for (int r = 0; r < 4; ++r) {
            S.sc.combs[r][cc_] = vals[r];
            out[917504 + ((size_t)(r0 + r) * 64 + step) * 7 + cc_] = vals[r];
          }
        }
      }
    }
    __syncthreads();
  }
}

extern "C" void kernel_launch(void* const* d_in, const int* in_sizes, int n_in,
                              void* d_out, int out_size, void* d_ws, size_t ws_size,
                              hipStream_t stream) {
  const float* tc       = (const float*)d_in[0];
  const float* cc       = (const float*)d_in[1];
  const float* initv    = (const float*)d_in[2];
  const float* W_cf     = (const float*)d_in[3];
  const float* b_cf     = (const float*)d_in[4];
  const float* ln_g     = (const float*)d_in[5];
  const float* ln_b     = (const float*)d_in[6];
  const float* W_feat   = (const float*)d_in[7];
  const float* b_feat   = (const float*)d_in[8];
  const float* W_inproj = (const float*)d_in[9];
  const float* b_inproj = (const float*)d_in[10];
  const float* conv_w   = (const float*)d_in[11];
  const float* conv_b   = (const float*)d_in[12];
  const float* W_xproj  = (const float*)d_in[13];
  const float* W_dt     = (const float*)d_in[14];
  const float* b_dt     = (const float*)d_in[15];
  const float* D_param  = (const float*)d_in[16];
  const float* W_out    = (const float*)d_in[17];
  const float* b_out    = (const float*)d_in[18];
  const float* W_tr     = (const float*)d_in[19];
  const float* b_tr     = (const float*)d_in[20];
  const float* W_se     = (const float*)d_in[21];
  const float* b_se     = (const float*)d_in[22];
  const float* W_fin    = (const float*)d_in[23];
  const float* b_fin    = (const float*)d_in[24];

  float* ws = (float*)d_ws;   // needs 536704 B

  hipLaunchKernelGGL(k_fold, dim3(397), dim3(256), 0, stream,
                     W_feat, W_inproj, W_out, W_tr, W_se, b_out, b_tr, b_se,
                     W_fin, b_fin, W_xproj, W_dt, ws);
  hipLaunchKernelGGL(k_scan, dim3(256), dim3(1024), 0, stream,
                     tc, cc, initv, W_cf, b_cf, ln_g, ln_b, W_feat, b_feat,
                     W_inproj, b_inproj, conv_w, conv_b, b_dt, D_param,
                     ws, (float*)d_out);
}